// Round 2
// baseline (54.426 us; speedup 1.0000x reference)
//
#include <hip/hip_runtime.h>

// Problem constants (reference: B=128, S=2048, D=128)
#define BB 128
#define SS 2048
#define DD 128
#define BS (BB * SS)

// ---------------------------------------------------------------------------
// Kernel A (prep): build pe[S][D] table AND visited_time via inverse-perm
// scatter (random 4B writes into a 2MB L2-resident array -> merged in L2).
//   vt[half][b][ sol[b][i] ] = i
// ---------------------------------------------------------------------------
__global__ __launch_bounds__(256) void prep_kernel(
        const int* __restrict__ sol, const int* __restrict__ best,
        float* __restrict__ pe, int* __restrict__ vt) {
    int idx = blockIdx.x * 256 + threadIdx.x;

    // task 1: pe table (262144 elements)
    if (idx < SS * DD) {
        int s = idx >> 7;          // row
        int j = idx & (DD - 1);    // col
        float expo = -(float)(2 * (j >> 1)) / (float)DD;
        float invf = powf(10000.0f, expo);
        float angle = (float)(s + 1) * invf;
        pe[idx] = (s == 0) ? angle : ((j & 1) ? cosf(angle) : sinf(angle));
    }

    // task 2: inverse permutations (2 * 262144 entries)
    if (idx < 2 * BS) {
        int half = (idx >= BS) ? 1 : 0;
        int k    = half ? idx - BS : idx;     // b*S + i
        int i    = k & (SS - 1);
        int node = half ? best[k] : sol[k];
        vt[half * BS + (k - i) + node] = i;   // visited_time[b][node] = i
    }
}

// ---------------------------------------------------------------------------
// Kernel B (gather): out[r][:] = pe[vt[r]][:] with SEQUENTIAL output writes.
// 32 lanes per row, each lane moves one float4 (512 B per row).
// ---------------------------------------------------------------------------
__global__ __launch_bounds__(256) void gather_kernel(
        const int* __restrict__ vt, const float* __restrict__ pe,
        float* __restrict__ out) {
    const int ROWS = 2 * BS;
    const int lane = threadIdx.x & 31;   // 32 lanes per row
    const int rib  = threadIdx.x >> 5;   // 8 rows per 256-thread block
    for (int r = blockIdx.x * 8 + rib; r < ROWS; r += gridDim.x * 8) {
        const int i = vt[r];                       // uniform within 32-lane group
        const float4* __restrict__ src = (const float4*)(pe + (size_t)i * DD);
        float4* __restrict__ dst = (float4*)(out + (size_t)r * DD);
        dst[lane] = src[lane];
    }
}

// ---------------------------------------------------------------------------
// Fallback (ws too small): direct scatter with on-the-fly trig.
// ---------------------------------------------------------------------------
__global__ __launch_bounds__(256) void scatter_fused_kernel(
        const int* __restrict__ sol, const int* __restrict__ best,
        float* __restrict__ out) {
    const int ROWS = 2 * BS;
    const int lane = threadIdx.x & 31;
    const int rib  = threadIdx.x >> 5;
    for (int r = blockIdx.x * 8 + rib; r < ROWS; r += gridDim.x * 8) {
        const int half = (r >= BS) ? 1 : 0;
        const int idx  = half ? (r - BS) : r;
        const int i    = idx & (SS - 1);
        const int node = half ? best[idx] : sol[idx];
        const int dstRow = half * BS + (idx - i) + node;
        float4 v;
        float* vp = (float*)&v;
        #pragma unroll
        for (int q = 0; q < 4; ++q) {
            int j = lane * 4 + q;
            float expo = -(float)(2 * (j >> 1)) / (float)DD;
            float invf = powf(10000.0f, expo);
            float angle = (float)(i + 1) * invf;
            if (i == 0) vp[q] = angle;
            else        vp[q] = (j & 1) ? cosf(angle) : sinf(angle);
        }
        ((float4*)(out + (size_t)dstRow * DD))[lane] = v;
    }
}

extern "C" void kernel_launch(void* const* d_in, const int* in_sizes, int n_in,
                              void* d_out, int out_size, void* d_ws, size_t ws_size,
                              hipStream_t stream) {
    // inputs: d_in[0] = x (f32, unused), d_in[1] = solutions, d_in[2] = best_solutions
    const int* sol  = (const int*)d_in[1];
    const int* best = (const int*)d_in[2];
    float* out = (float*)d_out;

    const size_t peBytes = (size_t)SS * DD * sizeof(float);     // 1 MiB
    const size_t vtBytes = (size_t)2 * BS * sizeof(int);        // 2 MiB

    if (ws_size >= peBytes + vtBytes) {
        float* pe = (float*)d_ws;
        int*   vt = (int*)((char*)d_ws + peBytes);
        // prep: covers max(SS*DD, 2*BS) = 524288 threads -> 2048 blocks
        prep_kernel<<<2048, 256, 0, stream>>>(sol, best, pe, vt);
        // gather: 524288 rows, 8 rows/block-iter, 8192 blocks -> 8 iters
        gather_kernel<<<8192, 256, 0, stream>>>(vt, pe, out);
    } else {
        scatter_fused_kernel<<<8192, 256, 0, stream>>>(sol, best, out);
    }
    (void)in_sizes; (void)n_in; (void)out_size;
}